// Round 4
// baseline (4236.290 us; speedup 1.0000x reference)
//
#include <hip/hip_runtime.h>

typedef __attribute__((ext_vector_type(4))) float f32x4;
typedef __attribute__((ext_vector_type(8))) short s16x8;

#define LOG2E 1.4426950408889634f

__device__ __forceinline__ unsigned short f2bf(float f) {
  union { float f; unsigned int i; } v; v.f = f;
  unsigned int u = v.i;
  u = (u + 0x7FFFu + ((u >> 16) & 1u)) >> 16;
  return (unsigned short)u;
}
__device__ __forceinline__ float bf2f(unsigned short s) {
  union { unsigned int i; float f; } v; v.i = ((unsigned int)s) << 16;
  return v.f;
}
__device__ __forceinline__ float sigm(float x) {
  return __builtin_amdgcn_rcpf(1.f + __builtin_amdgcn_exp2f(-LOG2E * x));
}
__device__ __forceinline__ float tanh_(float x) {
  return 1.f - 2.f * __builtin_amdgcn_rcpf(1.f + __builtin_amdgcn_exp2f(2.f * LOG2E * x));
}
__device__ __forceinline__ f32x4 mfma16(s16x8 a, s16x8 b, f32x4 c) {
  return __builtin_amdgcn_mfma_f32_16x16x32_bf16(a, b, c, 0, 0, 0);
}
__device__ __forceinline__ s16x8 pack8(const float* s) {
  s16x8 v;
#pragma unroll
  for (int j = 0; j < 8; ++j) v[j] = (short)f2bf(s[j]);
  return v;
}

// ---------------------------------------------------------------- ws-size diagnostic
__global__ void wsdbg_kernel(float* __restrict__ out, float v) { out[0] = v; }

// ---------------------------------------------------------------- gating (loss only)
__global__ void gating_kernel(const float* __restrict__ spk,
                              const float* __restrict__ wgw,
                              const float* __restrict__ wgb,
                              float* __restrict__ loss_out) {
  __shared__ __align__(16) float logits[32][8];
  __shared__ __align__(16) float gmat[32][8];
  const int tid = threadIdx.x;
  {
    const int b = tid >> 3, e = tid & 7;
    float s = wgb[e];
    for (int k = 0; k < 256; ++k) s += spk[b * 256 + k] * wgw[e * 256 + k];
    logits[b][e] = s;
  }
  __syncthreads();
  if (tid < 32) {
    const int b = tid;
    float v[8];
    for (int e = 0; e < 8; ++e) v[e] = logits[b][e];
    int idx[4]; float val[4];
    unsigned used = 0;
    for (int k = 0; k < 4; ++k) {
      float best = -1e30f; int bi = 0;
      for (int e = 0; e < 8; ++e)
        if (!((used >> e) & 1) && v[e] > best) { best = v[e]; bi = e; }
      used |= (1u << bi); idx[k] = bi; val[k] = best;
    }
    const float m = val[0];
    float ex[4], ssum = 0.f;
    for (int k = 0; k < 4; ++k) { ex[k] = __builtin_amdgcn_exp2f(LOG2E * (val[k] - m)); ssum += ex[k]; }
    for (int e = 0; e < 8; ++e) gmat[b][e] = 0.f;
    for (int k = 0; k < 4; ++k) gmat[b][idx[k]] = ex[k] / ssum;
  }
  __syncthreads();
  if (tid == 0) {
    float imp[8], ld[8];
    for (int e = 0; e < 8; ++e) {
      float si = 0.f, sl = 0.f;
      for (int b = 0; b < 32; ++b) { si += gmat[b][e]; sl += (gmat[b][e] > 0.f) ? 1.f : 0.f; }
      imp[e] = si; ld[e] = sl;
    }
    float mi = 0.f, ml = 0.f;
    for (int e = 0; e < 8; ++e) { mi += imp[e]; ml += ld[e]; }
    mi *= 0.125f; ml *= 0.125f;
    float vi = 0.f, vl = 0.f;
    for (int e = 0; e < 8; ++e) {
      vi += (imp[e] - mi) * (imp[e] - mi);
      vl += (ld[e] - ml) * (ld[e] - ml);
    }
    vi /= 7.f; vl /= 7.f;
    const float cvi = vi / (mi * mi + 1e-10f);
    const float cvl = vl / (ml * ml + 1e-10f);
    loss_out[0] = 0.01f * (cvi + cvl);
  }
}

// ---------------------------------------------------------------- M = fc_w @ fc1_w halves; C = fc_w@fc1_b + fc_b
__global__ void mprep_kernel(const float* __restrict__ fc1w, const float* __restrict__ fc1b,
                             const float* __restrict__ fcw, const float* __restrict__ fcb,
                             float* __restrict__ M, float* __restrict__ Cv) {
  const int tid = threadIdx.x;
  for (int mi = tid; mi < 12288; mi += 256) {   // [2][48][128]
    const int dd = mi / 6144, rem = mi % 6144, o = rem >> 7, hc = rem & 127;
    float s = 0.f;
    if (o < 44)
      for (int h = 0; h < 128; ++h) s += fcw[o * 128 + h] * fc1w[h * 256 + dd * 128 + hc];
    M[mi] = s;
  }
  if (tid < 44) {
    float s = fcb[tid];
    for (int h = 0; h < 128; ++h) s += fcw[tid * 128 + h] * fc1b[h];
    Cv[tid] = s;
  }
}

// ---------------------------------------------------------------- xW chunk GEMM
// grid 256 = (ed 16) x (tlb 16), 512 thr (8 waves x 64 cols).
// Writes xw[ed][sl][n 512][b 32] bf16 = x(t)@Wih^T + bias, t = d ? 1023-s : s.
template <bool L0>
__global__ __launch_bounds__(512, 1) void gemm_xw(
    const void* __restrict__ Ain, const float* __restrict__ W,
    const float* __restrict__ bih, const float* __restrict__ bhh,
    unsigned short* __restrict__ xwout, int c, int CLEN) {
  constexpr int KC = L0 ? 4 : 8;
  constexpr int KS = KC * 32;
  const int bx = blockIdx.x;
  const int ed = bx >> 4, tlb = bx & 15;
  const int e = ed >> 1, d = ed & 1;
  const int TLW = CLEN >> 4;
  const int tid = threadIdx.x, w = tid >> 6, l = tid & 63;
  const int l15 = l & 15, lq = l >> 4;

  s16x8 bf[4][KC];
  float bias[4];
#pragma unroll
  for (int nt = 0; nt < 4; ++nt) {
    const int n = w * 64 + nt * 16 + l15;
    bias[nt] = bih[ed * 512 + n] + bhh[ed * 512 + n];
    const float* wp = W + ((size_t)ed * 512 + n) * KS + lq * 8;
#pragma unroll
    for (int kc = 0; kc < KC; ++kc) bf[nt][kc] = pack8(wp + kc * 32);
  }
  for (int tl = 0; tl < TLW; ++tl) {
    const int sl = tlb * TLW + tl;
    const int s = c * CLEN + sl;
    const int t = d ? 1023 - s : s;
#pragma unroll
    for (int mt = 0; mt < 2; ++mt) {
      const int b = mt * 16 + l15;
      s16x8 af[KC];
      if (L0) {
        const float* ap = (const float*)Ain + ((size_t)b * 1024 + t) * 128 + lq * 8;
#pragma unroll
        for (int kc = 0; kc < KC; ++kc) af[kc] = pack8(ap + kc * 32);
      } else {
        const unsigned short* ap =
            (const unsigned short*)Ain + ((size_t)(e * 32 + b) * 1024 + t) * 256 + lq * 8;
#pragma unroll
        for (int kc = 0; kc < KC; ++kc) af[kc] = *(const s16x8*)(ap + kc * 32);
      }
      f32x4 acc[4];
#pragma unroll
      for (int nt = 0; nt < 4; ++nt) acc[nt] = {bias[nt], bias[nt], bias[nt], bias[nt]};
#pragma unroll
      for (int kc = 0; kc < KC; ++kc)
#pragma unroll
        for (int nt = 0; nt < 4; ++nt) acc[nt] = mfma16(af[kc], bf[nt][kc], acc[nt]);
      unsigned short* op = xwout + ((size_t)ed * CLEN + sl) * 16384 + mt * 16 + lq * 4;
#pragma unroll
      for (int nt = 0; nt < 4; ++nt) {
        const int n = w * 64 + nt * 16 + l15;
        ushort4 o4;
        o4.x = f2bf(acc[nt][0]); o4.y = f2bf(acc[nt][1]);
        o4.z = f2bf(acc[nt][2]); o4.w = f2bf(acc[nt][3]);
        *(ushort4*)(op + (size_t)n * 32) = o4;
      }
    }
  }
}

// ---------------------------------------------------------------- recurrent chunk
// grid 32 = (e,d,bh), 256 thr (4 waves). Per step: a = xw + h@Whh^T; gates; h.
// OUTP=false (layer0): write h to h0out. OUTP=true (layer1): fold g*M_d*h into outpriv.
// LDS h-feedback slot layout: frag elem (cell cc, k-chunk) -> byte
//   (cc>>5)*1024 + ((cc>>3)&3)*256 + row*16 + (cc&7)*2 ; read addr = kc*1024 + lane*16
//   (consecutive lanes -> consecutive 16B: conflict-free b128 reads).
template <bool OUTP>
__global__ __launch_bounds__(256, 1) void lstm_rec(
    const float* __restrict__ Whh,
    const unsigned short* __restrict__ xw,
    unsigned short* __restrict__ h0out,
    float* __restrict__ outpriv,
    const float* __restrict__ Mmat,
    const float* __restrict__ spk, const float* __restrict__ wgw,
    const float* __restrict__ wgb,
    unsigned short* __restrict__ hstate, float* __restrict__ cstate,
    int c, int CLEN, int first, int last) {
  __shared__ __align__(16) char hbf[2][4096];
  __shared__ __align__(16) float sgl[16][8];
  __shared__ __align__(16) float sgg[16][8];
  const int blk = blockIdx.x;
  const int e = blk >> 2, d = (blk >> 1) & 1, bh = blk & 1;
  const int ed = e * 2 + d;
  const int tid = threadIdx.x, w = tid >> 6, l = tid & 63;
  const int l15 = l & 15, lq = l >> 4;

  // ---- gates for this expert's 16 batch rows (OUTP only) ----
  float g4[4] = {0.f, 0.f, 0.f, 0.f};
  if constexpr (OUTP) {
    if (tid < 128) {
      const int bb = tid >> 3, ee = tid & 7;
      const float* sp = spk + (bh * 16 + bb) * 256;
      const float* wg = wgw + ee * 256;
      float s = wgb[ee];
      for (int k = 0; k < 256; ++k) s += sp[k] * wg[k];
      sgl[bb][ee] = s;
    }
    __syncthreads();
    if (tid < 16) {
      float v[8];
      for (int i = 0; i < 8; ++i) v[i] = sgl[tid][i];
      int idx[4]; float val[4]; unsigned used = 0;
      for (int k = 0; k < 4; ++k) {
        float best = -1e30f; int bi = 0;
        for (int i = 0; i < 8; ++i)
          if (!((used >> i) & 1) && v[i] > best) { best = v[i]; bi = i; }
        used |= 1u << bi; idx[k] = bi; val[k] = best;
      }
      float ex[4], ss = 0.f;
      for (int k = 0; k < 4; ++k) { ex[k] = __builtin_amdgcn_exp2f(LOG2E * (val[k] - val[0])); ss += ex[k]; }
      for (int i = 0; i < 8; ++i) sgg[tid][i] = 0.f;
      for (int k = 0; k < 4; ++k) sgg[tid][idx[k]] = ex[k] / ss;
    }
    __syncthreads();
    for (int r = 0; r < 4; ++r) g4[r] = sgg[lq * 4 + r][e];
  }

  // ---- weights (Whh B-fragments); n(q) = q*64 + w*16 + l15 ----
  s16x8 bfh[8][4];
#pragma unroll
  for (int q = 0; q < 8; ++q) {
    const int n = q * 64 + w * 16 + l15;
    const float* wp = Whh + ((size_t)ed * 512 + n) * 128 + lq * 8;
#pragma unroll
    for (int kc = 0; kc < 4; ++kc) bfh[q][kc] = pack8(wp + kc * 32);
  }
  s16x8 mfr[4];
  if constexpr (OUTP) {
    if (w < 3) {
      const float* mp = Mmat + ((size_t)d * 48 + w * 16 + l15) * 128 + lq * 8;
#pragma unroll
      for (int kc = 0; kc < 4; ++kc) mfr[kc] = pack8(mp + kc * 32);
    }
  }

  // ---- state ----
  const int cA = w * 16 + l15, cB = cA + 64;
  const int hbA = ((cA >> 5) << 10) + (((cA >> 3) & 3) << 8) + ((cA & 7) << 1) + lq * 64;
  const int hbB = ((cB >> 5) << 10) + (((cB >> 3) & 3) << 8) + ((cB & 7) << 1) + lq * 64;
  float cst[8];
  if (first) {
#pragma unroll
    for (int i = 0; i < 8; ++i) cst[i] = 0.f;
    s16x8 z;
#pragma unroll
    for (int j = 0; j < 8; ++j) z[j] = 0;
    *(s16x8*)(&hbf[0][tid * 16]) = z;
  } else {
    const float* cp = cstate + ((size_t)blk * 256 + tid) * 8;
#pragma unroll
    for (int i = 0; i < 8; ++i) cst[i] = cp[i];
    const unsigned short* hp = hstate + ((size_t)blk * 256 + tid) * 8;
#pragma unroll
    for (int r = 0; r < 4; ++r) {
      *(unsigned short*)(&hbf[0][hbA + r * 16]) = hp[r];
      *(unsigned short*)(&hbf[0][hbB + r * 16]) = hp[4 + r];
    }
  }
  __syncthreads();

  const unsigned short* xwl = xw + (size_t)(w * 16 + l15) * 32 + bh * 16 + lq * 4;
  const size_t xwch = (size_t)ed * CLEN;
  ushort4 xq[8];
#pragma unroll
  for (int q = 0; q < 8; ++q) xq[q] = *(const ushort4*)(xwl + xwch * 16384 + q * 2048);

  const size_t houtb = ((size_t)(e * 32 + bh * 16 + lq * 4) * 1024) * 256 + (size_t)d * 128;

  for (int tt = 0; tt < CLEN; ++tt) {
    const int p = tt & 1;
    const int s = c * CLEN + tt;

    // prefetch next step's xw
    ushort4 nxq[8];
    {
      int tn = tt + 1; if (tn >= CLEN) tn = CLEN - 1;
      const unsigned short* pn = xwl + (xwch + tn) * 16384;
#pragma unroll
      for (int q = 0; q < 8; ++q) nxq[q] = *(const ushort4*)(pn + q * 2048);
    }

    s16x8 hf[4];
#pragma unroll
    for (int kc = 0; kc < 4; ++kc) hf[kc] = *(const s16x8*)(&hbf[p][kc * 1024 + l * 16]);

    // fold previous step's h into private output (uses same hf fragments)
    if constexpr (OUTP) {
      if (w < 3) {
        f32x4 mo = {0.f, 0.f, 0.f, 0.f};
#pragma unroll
        for (int kc = 0; kc < 4; ++kc) mo = mfma16(hf[kc], mfr[kc], mo);
        const int o = w * 16 + l15;
        if (s > 0 && o < 44) {
          const int tp = d ? 1023 - (s - 1) : (s - 1);
#pragma unroll
          for (int r = 0; r < 4; ++r)
            outpriv[(((size_t)ed * 32 + bh * 16 + lq * 4 + r) * 1024 + tp) * 44 + o] = g4[r] * mo[r];
        }
      }
    }

    f32x4 a[8];
#pragma unroll
    for (int q = 0; q < 8; ++q) {
      a[q][0] = bf2f(xq[q].x); a[q][1] = bf2f(xq[q].y);
      a[q][2] = bf2f(xq[q].z); a[q][3] = bf2f(xq[q].w);
    }
#pragma unroll
    for (int kc = 0; kc < 4; ++kc)
#pragma unroll
      for (int q = 0; q < 8; ++q) a[q] = mfma16(hf[kc], bfh[q][kc], a[q]);

    // gates: q = gate*2 + cell; cells (cA, cB), rows lq*4+r
    unsigned short hb[8];
#pragma unroll
    for (int cell = 0; cell < 2; ++cell)
#pragma unroll
      for (int r = 0; r < 4; ++r) {
        const float gi = a[cell][r], gf = a[2 + cell][r], gg = a[4 + cell][r], go = a[6 + cell][r];
        const float cc = sigm(gf) * cst[cell * 4 + r] + sigm(gi) * tanh_(gg);
        cst[cell * 4 + r] = cc;
        hb[cell * 4 + r] = f2bf(sigm(go) * tanh_(cc));
      }

    char* hw = hbf[1 - p];
#pragma unroll
    for (int r = 0; r < 4; ++r) {
      *(unsigned short*)(hw + hbA + r * 16) = hb[r];
      *(unsigned short*)(hw + hbB + r * 16) = hb[4 + r];
    }
    if constexpr (!OUTP) {
      const int t = d ? 1023 - s : s;
#pragma unroll
      for (int r = 0; r < 4; ++r) {
        h0out[houtb + (size_t)r * 1024 * 256 + (size_t)t * 256 + cA] = hb[r];
        h0out[houtb + (size_t)r * 1024 * 256 + (size_t)t * 256 + cB] = hb[4 + r];
      }
    }
    if (tt == CLEN - 1) {
      unsigned short* hp = hstate + ((size_t)blk * 256 + tid) * 8;
      float* cp = cstate + ((size_t)blk * 256 + tid) * 8;
#pragma unroll
      for (int i = 0; i < 8; ++i) { hp[i] = hb[i]; cp[i] = cst[i]; }
    }
    __syncthreads();
#pragma unroll
    for (int q = 0; q < 8; ++q) xq[q] = nxq[q];
  }

  // epilogue: output for the final step's h (last chunk only)
  if constexpr (OUTP) {
    if (last && w < 3) {
      s16x8 hf[4];
#pragma unroll
      for (int kc = 0; kc < 4; ++kc) hf[kc] = *(const s16x8*)(&hbf[0][kc * 1024 + l * 16]);
      f32x4 mo = {0.f, 0.f, 0.f, 0.f};
#pragma unroll
      for (int kc = 0; kc < 4; ++kc) mo = mfma16(hf[kc], mfr[kc], mo);
      const int o = w * 16 + l15;
      if (o < 44) {
        const int tp = d ? 0 : 1023;
#pragma unroll
        for (int r = 0; r < 4; ++r)
          outpriv[(((size_t)ed * 32 + bh * 16 + lq * 4 + r) * 1024 + tp) * 44 + o] = g4[r] * mo[r];
      }
    }
  }
}

// ---------------------------------------------------------------- final reduce
__global__ __launch_bounds__(256) void reduce_kernel(
    const float* __restrict__ outpriv, const float* __restrict__ Cv,
    float* __restrict__ out) {
  const int i = blockIdx.x * 256 + threadIdx.x;
  if (i >= 1441792) return;
  const int o = i % 44;
  const int bt = i / 44;
  const int b = bt & 31, t = bt >> 5;
  float s = Cv[o];
  const float* pp = outpriv + ((size_t)b * 1024 + t) * 44 + o;
#pragma unroll
  for (int ed = 0; ed < 16; ++ed) s += pp[(size_t)ed * 1441792];
  out[((size_t)t * 32 + b) * 44 + o] = s;
}

// ---------------------------------------------------------------- launch
extern "C" void kernel_launch(void* const* d_in, const int* in_sizes, int n_in,
                              void* d_out, int out_size, void* d_ws, size_t ws_size,
                              hipStream_t stream) {
  const float* x    = (const float*)d_in[0];
  const float* spk  = (const float*)d_in[1];
  const float* wgw  = (const float*)d_in[2];
  const float* wgb  = (const float*)d_in[3];
  const float* Wih0 = (const float*)d_in[4];
  const float* Whh0 = (const float*)d_in[5];
  const float* bih0 = (const float*)d_in[6];
  const float* bhh0 = (const float*)d_in[7];
  const float* Wih1 = (const float*)d_in[8];
  const float* Whh1 = (const float*)d_in[9];
  const float* bih1 = (const float*)d_in[10];
  const float* bhh1 = (const float*)d_in[11];
  const float* fc1w = (const float*)d_in[12];
  const float* fc1b = (const float*)d_in[13];
  const float* fcw  = (const float*)d_in[14];
  const float* fcb  = (const float*)d_in[15];
  float* out = (float*)d_out;

  // ws layout (bytes):
  //   [0,          134217728)  h0   bf16 [8e][32b][1024t][256f]
  //   [134217728,  201326592)  xw   chunk region (l0: 67MB @128 steps; l1: 33.5MB @64)
  //   [167772160,  260046848)  outpriv f32 [16ed][32b][1024t][44]  (written after l0)
  //   [260046848,  260177920)  hstate bf16 [32][256][8]
  //   [260177920,  260440064)  cstate f32  [32][256][8]
  //   [260440064,  260489216)  M f32 [2][48][128]
  //   [260489216,  260489392)  C f32 [44]
  const size_t NEED = 260489392;
  if (ws_size < NEED) {
    wsdbg_kernel<<<1, 1, 0, stream>>>(out, (float)(ws_size >> 20));
    return;
  }
  char* ws = (char*)d_ws;
  unsigned short* hbuf   = (unsigned short*)ws;
  unsigned short* xw     = (unsigned short*)(ws + 134217728);
  float*          outpr  = (float*)(ws + 167772160);
  unsigned short* hstate = (unsigned short*)(ws + 260046848);
  float*          cstate = (float*)(ws + 260177920);
  float*          Mmat   = (float*)(ws + 260440064);
  float*          Cv     = (float*)(ws + 260489216);

  gating_kernel<<<1, 256, 0, stream>>>(spk, wgw, wgb, out + 1441792);
  mprep_kernel<<<1, 256, 0, stream>>>(fc1w, fc1b, fcw, fcb, Mmat, Cv);

  for (int c = 0; c < 8; ++c) {
    gemm_xw<true><<<256, 512, 0, stream>>>(x, Wih0, bih0, bhh0, xw, c, 128);
    lstm_rec<false><<<32, 256, 0, stream>>>(Whh0, xw, hbuf, nullptr, nullptr,
                                            nullptr, nullptr, nullptr,
                                            hstate, cstate, c, 128, c == 0, c == 7);
  }
  for (int c = 0; c < 16; ++c) {
    gemm_xw<false><<<256, 512, 0, stream>>>(hbuf, Wih1, bih1, bhh1, xw, c, 64);
    lstm_rec<true><<<32, 256, 0, stream>>>(Whh1, xw, nullptr, outpr, Mmat,
                                           spk, wgw, wgb,
                                           hstate, cstate, c, 64, c == 0, c == 15);
  }
  reduce_kernel<<<5632, 256, 0, stream>>>(outpr, Cv, out);
}

// Round 6
// 2409.132 us; speedup vs baseline: 1.7584x; 1.7584x over previous
//
#include <hip/hip_runtime.h>

typedef __attribute__((ext_vector_type(4))) float f32x4;
typedef __attribute__((ext_vector_type(8))) short s16x8;

#define LOG2E 1.4426950408889634f

__device__ __forceinline__ unsigned short f2bf(float f) {
  union { float f; unsigned int i; } v; v.f = f;
  unsigned int u = v.i;
  u = (u + 0x7FFFu + ((u >> 16) & 1u)) >> 16;
  return (unsigned short)u;
}
__device__ __forceinline__ float bf2f(unsigned short s) {
  union { unsigned int i; float f; } v; v.i = ((unsigned int)s) << 16;
  return v.f;
}
__device__ __forceinline__ float rcp_(float x) { return __builtin_amdgcn_rcpf(x); }
__device__ __forceinline__ float ex2(float x) { return __builtin_amdgcn_exp2f(x); }
__device__ __forceinline__ f32x4 mfma16(s16x8 a, s16x8 b, f32x4 c) {
  return __builtin_amdgcn_mfma_f32_16x16x32_bf16(a, b, c, 0, 0, 0);
}
__device__ __forceinline__ s16x8 pack8(const float* s) {
  s16x8 v;
#pragma unroll
  for (int j = 0; j < 8; ++j) v[j] = (short)f2bf(s[j]);
  return v;
}

// ws offsets (bytes)
#define OFF_H0  0
#define OFF_XW  134217728
#define OFF_XT  201326592
#define OFF_WHH 209715200
#define OFF_HST 213909504
#define OFF_CST 214040576
#define OFF_M   214564864
#define OFF_CV  214614016
#define OFF_G   214614272
#define WS_NEED 214615296

// ---------------------------------------------------------------- ws diag
__global__ void wsdbg_kernel(float* __restrict__ out, float v) { out[0] = v; }

// ---------------------------------------------------------------- prep: Whh -> bf16
// Whh0, Whh1 are each [8][2][512][128] = 1,048,576 floats. whhb = [2 layers][...].
__global__ void prepw_kernel(const float* __restrict__ Whh0, const float* __restrict__ Whh1,
                             unsigned short* __restrict__ whhb) {
  const int i = blockIdx.x * 512 + threadIdx.x;  // 2,097,152 threads, 1 elem each
  if (i < 2097152)
    whhb[i] = f2bf(i < 1048576 ? Whh0[i] : Whh1[i - 1048576]);
}

// ---------------------------------------------------------------- prep: x -> xt bf16 [t][b][128]
__global__ void prepx_kernel(const float* __restrict__ x, unsigned short* __restrict__ xt) {
  const int i = blockIdx.x * 512 + threadIdx.x;
  for (int j = i; j < 4194304; j += 2097152) {
    const int b = j >> 17, rem = j & 131071, t = rem >> 7, f = rem & 127;
    xt[((size_t)t * 32 + b) * 128 + f] = f2bf(x[j]);
  }
}

// ---------------------------------------------------------------- prep: M = fc_w @ fc1_w halves; Cv = fc_w@fc1_b + fc_b
__global__ void mprep_kernel(const float* __restrict__ fc1w, const float* __restrict__ fc1b,
                             const float* __restrict__ fcw, const float* __restrict__ fcb,
                             float* __restrict__ M, float* __restrict__ Cv) {
  const int mi = blockIdx.x * 256 + threadIdx.x;  // grid 48
  if (mi < 12288) {  // [2][48][128]
    const int dd = mi / 6144, rem = mi % 6144, o = rem >> 7, hc = rem & 127;
    float s = 0.f;
    if (o < 44)
      for (int h = 0; h < 128; ++h) s += fcw[o * 128 + h] * fc1w[h * 256 + dd * 128 + hc];
    M[mi] = s;
  }
  if (blockIdx.x == 0 && threadIdx.x < 44) {
    const int o = threadIdx.x;
    float s = fcb[o];
    for (int h = 0; h < 128; ++h) s += fcw[o * 128 + h] * fc1b[h];
    Cv[o] = s;
  }
}

// ---------------------------------------------------------------- out init: out[t,b,o] = Cv[o]
__global__ void initout_kernel(const float* __restrict__ Cv, float* __restrict__ out) {
  const int i = blockIdx.x * 512 + threadIdx.x;
  if (i < 1441792) out[i] = Cv[i % 44];
}

// ---------------------------------------------------------------- gating: gates + loss
__global__ void gating_kernel(const float* __restrict__ spk,
                              const float* __restrict__ wgw,
                              const float* __restrict__ wgb,
                              float* __restrict__ gates_out,
                              float* __restrict__ loss_out) {
  __shared__ __align__(16) float logits[32][8];
  __shared__ __align__(16) float gmat[32][8];
  const int tid = threadIdx.x;
  {
    const int b = tid >> 3, e = tid & 7;
    float s = wgb[e];
    for (int k = 0; k < 256; ++k) s += spk[b * 256 + k] * wgw[e * 256 + k];
    logits[b][e] = s;
  }
  __syncthreads();
  if (tid < 32) {
    const int b = tid;
    float v[8];
    for (int e = 0; e < 8; ++e) v[e] = logits[b][e];
    int idx[4]; float val[4];
    unsigned used = 0;
    for (int k = 0; k < 4; ++k) {
      float best = -1e30f; int bi = 0;
      for (int e = 0; e < 8; ++e)
        if (!((used >> e) & 1) && v[e] > best) { best = v[e]; bi = e; }
      used |= (1u << bi); idx[k] = bi; val[k] = best;
    }
    const float m = val[0];
    float ex[4], ssum = 0.f;
    for (int k = 0; k < 4; ++k) { ex[k] = ex2(LOG2E * (val[k] - m)); ssum += ex[k]; }
    for (int e = 0; e < 8; ++e) gmat[b][e] = 0.f;
    for (int k = 0; k < 4; ++k) gmat[b][idx[k]] = ex[k] / ssum;
    for (int e = 0; e < 8; ++e) gates_out[b * 8 + e] = gmat[b][e];
  }
  __syncthreads();
  if (tid == 0) {
    float imp[8], ld[8];
    for (int e = 0; e < 8; ++e) {
      float si = 0.f, sl = 0.f;
      for (int b = 0; b < 32; ++b) { si += gmat[b][e]; sl += (gmat[b][e] > 0.f) ? 1.f : 0.f; }
      imp[e] = si; ld[e] = sl;
    }
    float mi = 0.f, ml = 0.f;
    for (int e = 0; e < 8; ++e) { mi += imp[e]; ml += ld[e]; }
    mi *= 0.125f; ml *= 0.125f;
    float vi = 0.f, vl = 0.f;
    for (int e = 0; e < 8; ++e) {
      vi += (imp[e] - mi) * (imp[e] - mi);
      vl += (ld[e] - ml) * (ld[e] - ml);
    }
    vi /= 7.f; vl /= 7.f;
    loss_out[0] = 0.01f * (vi / (mi * mi + 1e-10f) + vl / (ml * ml + 1e-10f));
  }
}

// ---------------------------------------------------------------- fused gemm + rec
// grid 256 x 512thr. blocks >=32: gemm for chunk k (skip if k>=16).
// blocks <32: recurrence for chunk k-1 (skip if k==0).
// xw layout: ushort [ed2=ed*2+bh][64 ss][512 n][16 b]; n = gate*128 + cell.
// LDS h slot: h[b][cell] at byte (cell>>5)<<10 | ((cell>>3)&3)<<8 | b<<4 | (cell&7)<<1
//   -> A-frag read addr = kc*1024 + lane*16 (contiguous, conflict-free).
template <int L>
__global__ __launch_bounds__(512, 1) void fused(
    int k,
    const unsigned short* __restrict__ Asrc,
    const float* __restrict__ Wih, const float* __restrict__ bihp, const float* __restrict__ bhhp,
    const unsigned short* __restrict__ whhb,
    unsigned short* __restrict__ xwbufs,
    unsigned short* __restrict__ hstate, float* __restrict__ cstate,
    unsigned short* __restrict__ h0out,
    const float* __restrict__ Mmat, const float* __restrict__ gatesp,
    float* __restrict__ outp) {
  constexpr int KC = L ? 8 : 4;
  constexpr int KS = KC * 32;
  const int tid = threadIdx.x, w = tid >> 6, l = tid & 63;
  const int l15 = l & 15, lq = l >> 4;

  if (blockIdx.x >= 32) {
    // ================= GEMM role: xw chunk k =================
    if (k >= 16) return;
    const int gb = blockIdx.x - 32;          // 0..223
    const int ed = gb & 15, e = ed >> 1, d = ed & 1;
    const int slice = gb >> 4;               // 0..13
    unsigned short* xw = xwbufs + (size_t)(k & 1) * 16777216;

    s16x8 bf[4][KC];
    float bias[4];
#pragma unroll
    for (int j = 0; j < 4; ++j) {
      const int n = w * 64 + j * 16 + l15;
      bias[j] = bihp[ed * 512 + n] + bhhp[ed * 512 + n];
      const float* wp = Wih + ((size_t)ed * 512 + n) * KS + lq * 8;
#pragma unroll
      for (int kc = 0; kc < KC; ++kc) bf[j][kc] = pack8(wp + kc * 32);
    }
    for (int ss = slice; ss < 64; ss += 14) {
      const int s = k * 64 + ss;
      const int t = d ? 1023 - s : s;
#pragma unroll
      for (int mt = 0; mt < 2; ++mt) {
        const size_t arow = (size_t)(L ? (e * 1024 + t) : t) * 32 + mt * 16 + l15;
        const unsigned short* ap = Asrc + arow * KS + lq * 8;
        s16x8 af[KC];
#pragma unroll
        for (int kc = 0; kc < KC; ++kc) af[kc] = *(const s16x8*)(ap + kc * 32);
        f32x4 acc[4];
#pragma unroll
        for (int j = 0; j < 4; ++j) acc[j] = f32x4{bias[j], bias[j], bias[j], bias[j]};
#pragma unroll
        for (int kc = 0; kc < KC; ++kc) {
#pragma unroll
          for (int j = 0; j < 4; ++j) acc[j] = mfma16(af[kc], bf[j][kc], acc[j]);
        }
        unsigned short* op = xw + (((size_t)(ed * 2 + mt) * 64 + ss) * 512) * 16 + lq * 4;
#pragma unroll
        for (int j = 0; j < 4; ++j) {
          const int n = w * 64 + j * 16 + l15;
          ushort4 o4;
          o4.x = f2bf(acc[j][0]); o4.y = f2bf(acc[j][1]);
          o4.z = f2bf(acc[j][2]); o4.w = f2bf(acc[j][3]);
          *(ushort4*)(op + (size_t)n * 16) = o4;
        }
      }
    }
    return;
  }

  // ================= REC role: chunk c = k-1 =================
  if (k == 0) return;
  const int c = k - 1;
  const int rb = blockIdx.x, ed2 = rb >> 1, bh = rb & 1;
  const int e = ed2 >> 1, d = ed2 & 1;
  __shared__ __align__(16) char hbf[2][4096];
  const int cell = w * 16 + l15;

  // Whh B-frags (prepacked bf16): n(g) = g*128 + cell
  s16x8 bfh[4][4];
#pragma unroll
  for (int g = 0; g < 4; ++g) {
    const unsigned short* wp = whhb + ((size_t)ed2 * 512 + g * 128 + cell) * 128 + lq * 8;
#pragma unroll
    for (int kc = 0; kc < 4; ++kc) bfh[g][kc] = *(const s16x8*)(wp + kc * 32);
  }
  s16x8 mfr[4];
  float g4[4] = {0.f, 0.f, 0.f, 0.f};
  if constexpr (L) {
    if (w < 3) {
      const float* mp = Mmat + ((size_t)d * 48 + w * 16 + l15) * 128 + lq * 8;
#pragma unroll
      for (int kc = 0; kc < 4; ++kc) mfr[kc] = pack8(mp + kc * 32);
    }
#pragma unroll
    for (int r = 0; r < 4; ++r) g4[r] = gatesp[(bh * 16 + lq * 4 + r) * 8 + e];
  }

  const int wbase = ((cell >> 5) << 10) | (((cell >> 3) & 3) << 8) | ((cell & 7) << 1);
  float cst[4];
  if (c == 0) {
#pragma unroll
    for (int r = 0; r < 4; ++r) cst[r] = 0.f;
    if (tid < 256) {
      s16x8 z = {0, 0, 0, 0, 0, 0, 0, 0};
      *(s16x8*)(&hbf[0][tid * 16]) = z;
    }
  } else {
    const float* cp = cstate + ((size_t)rb * 512 + tid) * 4;
    const unsigned short* hp = hstate + ((size_t)rb * 512 + tid) * 4;
#pragma unroll
    for (int r = 0; r < 4; ++r) {
      cst[r] = cp[r];
      *(unsigned short*)(&hbf[0][wbase + (lq * 4 + r) * 16]) = hp[r];
    }
  }
  __syncthreads();

  const unsigned short* xwr = xwbufs + (size_t)(c & 1) * 16777216;
  const unsigned short* xwb = xwr + ((size_t)(ed2 * 2 + bh) * 64) * 8192 + cell * 16 + lq * 4;
  const size_t hob = (size_t)e * 8388608 + (size_t)(bh * 16 + lq * 4) * 256 + (size_t)d * 128 + cell;

  ushort4 xqA[4], xqB[4];
#pragma unroll
  for (int g = 0; g < 4; ++g) {
    xqA[g] = *(const ushort4*)(xwb + g * 2048);
    xqB[g] = *(const ushort4*)(xwb + 8192 + g * 2048);
  }

  auto step = [&](int tt, ushort4* xq, int tpre) {
    const int p = tt & 1;
    s16x8 hf[4];
#pragma unroll
    for (int kc = 0; kc < 4; ++kc) hf[kc] = *(const s16x8*)(&hbf[p][kc * 1024 + l * 16]);
    f32x4 a[4];
#pragma unroll
    for (int g = 0; g < 4; ++g) {
      a[g][0] = bf2f(xq[g].x); a[g][1] = bf2f(xq[g].y);
      a[g][2] = bf2f(xq[g].z); a[g][3] = bf2f(xq[g].w);
    }
    if (tpre < 64) {
#pragma unroll
      for (int g = 0; g < 4; ++g) xq[g] = *(const ushort4*)(xwb + (size_t)tpre * 8192 + g * 2048);
    }
    f32x4 mo = {0.f, 0.f, 0.f, 0.f};
    if constexpr (L) {
      if (w < 3) {
#pragma unroll
        for (int kc = 0; kc < 4; ++kc) mo = mfma16(hf[kc], mfr[kc], mo);
      }
    }
#pragma unroll
    for (int kc = 0; kc < 4; ++kc) {
#pragma unroll
      for (int g = 0; g < 4; ++g) a[g] = mfma16(hf[kc], bfh[g][kc], a[g]);
    }
    const int s = c * 64 + tt;
    unsigned short hb4[4];
#pragma unroll
    for (int r = 0; r < 4; ++r) {
      const float gi = a[0][r], gf = a[1][r], gg = a[2][r], go = a[3][r];
      const float ai = ex2(-LOG2E * gi);
      const float af2 = ex2(-LOG2E * gf);
      const float ao = ex2(-LOG2E * go);
      const float bg = ex2(fminf(2.f * LOG2E * gg, 126.f));
      const float sf = rcp_(1.f + af2);
      const float itg = (bg - 1.f) * rcp_((1.f + ai) * (1.f + bg));
      const float cc = sf * cst[r] + itg;
      cst[r] = cc;
      const float qc = ex2(fminf(2.f * LOG2E * cc, 126.f));
      const float hv = (qc - 1.f) * rcp_((1.f + ao) * (1.f + qc));
      hb4[r] = f2bf(hv);
    }
    char* hw = &hbf[1 - p][0];
#pragma unroll
    for (int r = 0; r < 4; ++r) *(unsigned short*)(hw + wbase + (lq * 4 + r) * 16) = hb4[r];
    if constexpr (!L) {
      const int t = d ? 1023 - s : s;
      unsigned short* hp = h0out + hob + (size_t)t * 8192;
#pragma unroll
      for (int r = 0; r < 4; ++r) hp[r * 256] = hb4[r];
    } else {
      if (w < 3 && s > 0) {
        const int o = w * 16 + l15;
        if (o < 44) {
          const int tp = d ? (1024 - s) : (s - 1);
#pragma unroll
          for (int r = 0; r < 4; ++r)
            atomicAdd(&outp[((size_t)tp * 32 + bh * 16 + lq * 4 + r) * 44 + o], g4[r] * mo[r]);
        }
      }
    }
    if (tt == 63) {
      unsigned short* hsp = hstate + ((size_t)rb * 512 + tid) * 4;
      float* csp = cstate + ((size_t)rb * 512 + tid) * 4;
#pragma unroll
      for (int r = 0; r < 4; ++r) { hsp[r] = hb4[r]; csp[r] = cst[r]; }
    }
    __syncthreads();
  };

  for (int t2 = 0; t2 < 64; t2 += 2) {
    step(t2, xqA, t2 + 2);
    step(t2 + 1, xqB, t2 + 3);
  }

  if constexpr (L) {
    // epilogue: fold h(s=1023) (sits in hbf[0] after tt=63)
    if (k == 16 && w < 3) {
      s16x8 hf[4];
#pragma unroll
      for (int kc = 0; kc < 4; ++kc) hf[kc] = *(const s16x8*)(&hbf[0][kc * 1024 + l * 16]);
      f32x4 mo = {0.f, 0.f, 0.f, 0.f};
#pragma unroll
      for (int kc = 0; kc < 4; ++kc) mo = mfma16(hf[kc], mfr[kc], mo);
      const int o = w * 16 + l15;
      if (o < 44) {
        const int tp = d ? 0 : 1023;
#pragma unroll
        for (int r = 0; r < 4; ++r)
          atomicAdd(&outp[((size_t)tp * 32 + bh * 16 + lq * 4 + r) * 44 + o], g4[r] * mo[r]);
      }
    }
  }
}

// ---------------------------------------------------------------- launch
extern "C" void kernel_launch(void* const* d_in, const int* in_sizes, int n_in,
                              void* d_out, int out_size, void* d_ws, size_t ws_size,
                              hipStream_t stream) {
  const float* x    = (const float*)d_in[0];
  const float* spk  = (const float*)d_in[1];
  const float* wgw  = (const float*)d_in[2];
  const float* wgb  = (const float*)d_in[3];
  const float* Wih0 = (const float*)d_in[4];
  const float* Whh0 = (const float*)d_in[5];
  const float* bih0 = (const float*)d_in[6];
  const float* bhh0 = (const float*)d_in[7];
  const float* Wih1 = (const float*)d_in[8];
  const float* Whh1 = (const float*)d_in[9];
  const float* bih1 = (const float*)d_in[10];
  const float* bhh1 = (const float*)d_in[11];
  const float* fc1w = (const float*)d_in[12];
  const float* fc1b = (const float*)d_in[13];
  const float* fcw  = (const float*)d_in[14];
  const float* fcb  = (const float*)d_in[15];
  float* out = (float*)d_out;

  if (ws_size < (size_t)WS_NEED) {
    wsdbg_kernel<<<1, 1, 0, stream>>>(out, (float)(ws_size >> 20));
    return;
  }
  char* ws = (char*)d_ws;
  unsigned short* h0     = (unsigned short*)(ws + OFF_H0);
  unsigned short* xwbufs = (unsigned short*)(ws + OFF_XW);
  unsigned short* xt     = (unsigned short*)(ws + OFF_XT);
  unsigned short* whhb   = (unsigned short*)(ws + OFF_WHH);
  unsigned short* hstate = (unsigned short*)(ws + OFF_HST);
  float*          cstate = (float*)(ws + OFF_CST);
  float*          Mmat   = (float*)(ws + OFF_M);
  float*          Cv     = (float*)(ws + OFF_CV);
  float*          gatesw = (float*)(ws + OFF_G);

  prepw_kernel<<<4096, 512, 0, stream>>>(Whh0, Whh1, whhb);
  prepx_kernel<<<4096, 512, 0, stream>>>(x, xt);
  mprep_kernel<<<48, 256, 0, stream>>>(fc1w, fc1b, fcw, fcb, Mmat, Cv);
  initout_kernel<<<2816, 512, 0, stream>>>(Cv, out);
  gating_kernel<<<1, 256, 0, stream>>>(spk, wgw, wgb, gatesw, out + 1441792);

  for (int k = 0; k <= 16; ++k)
    fused<0><<<256, 512, 0, stream>>>(k, xt, Wih0, bih0, bhh0, whhb, xwbufs,
                                      hstate, cstate, h0, nullptr, nullptr, out);
  for (int k = 0; k <= 16; ++k)
    fused<1><<<256, 512, 0, stream>>>(k, h0, Wih1, bih1, bhh1, whhb + 1048576, xwbufs,
                                      hstate, cstate, nullptr, Mmat, gatesw, out);
}

// Round 7
// 2075.969 us; speedup vs baseline: 2.0406x; 1.1605x over previous
//
#include <hip/hip_runtime.h>

typedef __attribute__((ext_vector_type(4))) float f32x4;
typedef __attribute__((ext_vector_type(8))) short s16x8;

#define LOG2E 1.4426950408889634f
#define K2L   2.8853900817779268f  /* 2*log2(e) */

__device__ __forceinline__ unsigned short f2bf(float f) {
  union { float f; unsigned int i; } v; v.f = f;
  unsigned int u = v.i;
  u = (u + 0x7FFFu + ((u >> 16) & 1u)) >> 16;
  return (unsigned short)u;
}
__device__ __forceinline__ float bf2f(unsigned short s) {
  union { unsigned int i; float f; } v; v.i = ((unsigned int)s) << 16;
  return v.f;
}
__device__ __forceinline__ float rcp_(float x) { return __builtin_amdgcn_rcpf(x); }
__device__ __forceinline__ float ex2(float x) { return __builtin_amdgcn_exp2f(x); }
__device__ __forceinline__ f32x4 mfma16(s16x8 a, s16x8 b, f32x4 c) {
  return __builtin_amdgcn_mfma_f32_16x16x32_bf16(a, b, c, 0, 0, 0);
}
__device__ __forceinline__ s16x8 pack8s(const float* s, float sc) {
  s16x8 v;
#pragma unroll
  for (int j = 0; j < 8; ++j) v[j] = (short)f2bf(s[j] * sc);
  return v;
}

// ws offsets (bytes)
#define OFF_H0   0            /* 134217728: h0 bf16 [8e][1024t][32b][256] */
#define OFF_XW   134217728    /* 67108864: 2 x 32MB xw ring */
#define OFF_XT   201326592    /* 8388608: xt bf16 [1024t][32b][128] */
#define OFF_WHH  209715200    /* 4194304: whhb bf16 (pre-scaled) */
#define OFF_H1C  213909504    /* 16777216: 2 x 8MB h1 chunk [8e][64ss][32b][256] */
#define OFF_HST  230686720    /* 131072 */
#define OFF_CST  230817792    /* 262144 */
#define OFF_M    231079936    /* 49152: M f32 [2][48][128] */
#define OFF_CV   231129088    /* 256 */
#define OFF_G    231129344    /* 1024 */
#define WS_NEED  231130368

// ---------------------------------------------------------------- ws diag
__global__ void wsdbg_kernel(float* __restrict__ out, float v) { out[0] = v; }

// ---------------------------------------------------------------- prep: Whh -> bf16, pre-scaled per gate row
__global__ void prepw_kernel(const float* __restrict__ Whh0, const float* __restrict__ Whh1,
                             unsigned short* __restrict__ whhb) {
  const int i = blockIdx.x * 512 + threadIdx.x;  // 2,097,152 threads
  if (i < 2097152) {
    const int gate = (i >> 14) & 3;  // [ed2][n=g*128+cell][k]
    const float sc = (gate == 2) ? K2L : -LOG2E;
    whhb[i] = f2bf((i < 1048576 ? Whh0[i] : Whh1[i - 1048576]) * sc);
  }
}

// ---------------------------------------------------------------- prep: x -> xt bf16 [t][b][128]
__global__ void prepx_kernel(const float* __restrict__ x, unsigned short* __restrict__ xt) {
  const int i = blockIdx.x * 512 + threadIdx.x;
  for (int j = i; j < 4194304; j += 2097152) {
    const int b = j >> 17, rem = j & 131071, t = rem >> 7, f = rem & 127;
    xt[((size_t)t * 32 + b) * 128 + f] = f2bf(x[j]);
  }
}

// ---------------------------------------------------------------- prep: M = fc_w @ fc1_w halves; Cv = fc_w@fc1_b + fc_b
__global__ void mprep_kernel(const float* __restrict__ fc1w, const float* __restrict__ fc1b,
                             const float* __restrict__ fcw, const float* __restrict__ fcb,
                             float* __restrict__ M, float* __restrict__ Cv) {
  const int mi = blockIdx.x * 256 + threadIdx.x;  // grid 48
  if (mi < 12288) {  // [2][48][128]
    const int dd = mi / 6144, rem = mi % 6144, o = rem >> 7, hc = rem & 127;
    float s = 0.f;
    if (o < 44)
      for (int h = 0; h < 128; ++h) s += fcw[o * 128 + h] * fc1w[h * 256 + dd * 128 + hc];
    M[mi] = s;
  }
  if (blockIdx.x == 0 && threadIdx.x < 44) {
    const int o = threadIdx.x;
    float s = fcb[o];
    for (int h = 0; h < 128; ++h) s += fcw[o * 128 + h] * fc1b[h];
    Cv[o] = s;
  }
}

// ---------------------------------------------------------------- out init: out[t,b,o] = Cv[o]
__global__ void initout_kernel(const float* __restrict__ Cv, float* __restrict__ out) {
  const int i = blockIdx.x * 512 + threadIdx.x;
  if (i < 1441792) out[i] = Cv[i % 44];
}

// ---------------------------------------------------------------- gating: gates + loss
__global__ void gating_kernel(const float* __restrict__ spk,
                              const float* __restrict__ wgw,
                              const float* __restrict__ wgb,
                              float* __restrict__ gates_out,
                              float* __restrict__ loss_out) {
  __shared__ __align__(16) float logits[32][8];
  __shared__ __align__(16) float gmat[32][8];
  const int tid = threadIdx.x;
  {
    const int b = tid >> 3, e = tid & 7;
    float s = wgb[e];
    for (int k = 0; k < 256; ++k) s += spk[b * 256 + k] * wgw[e * 256 + k];
    logits[b][e] = s;
  }
  __syncthreads();
  if (tid < 32) {
    const int b = tid;
    float v[8];
    for (int e = 0; e < 8; ++e) v[e] = logits[b][e];
    int idx[4]; float val[4];
    unsigned used = 0;
    for (int k = 0; k < 4; ++k) {
      float best = -1e30f; int bi = 0;
      for (int e = 0; e < 8; ++e)
        if (!((used >> e) & 1) && v[e] > best) { best = v[e]; bi = e; }
      used |= (1u << bi); idx[k] = bi; val[k] = best;
    }
    const float m = val[0];
    float ex[4], ssum = 0.f;
    for (int k = 0; k < 4; ++k) { ex[k] = ex2(LOG2E * (val[k] - m)); ssum += ex[k]; }
    for (int e = 0; e < 8; ++e) gmat[b][e] = 0.f;
    for (int k = 0; k < 4; ++k) gmat[b][idx[k]] = ex[k] / ssum;
    for (int e = 0; e < 8; ++e) gates_out[b * 8 + e] = gmat[b][e];
  }
  __syncthreads();
  if (tid == 0) {
    float imp[8], ld[8];
    for (int e = 0; e < 8; ++e) {
      float si = 0.f, sl = 0.f;
      for (int b = 0; b < 32; ++b) { si += gmat[b][e]; sl += (gmat[b][e] > 0.f) ? 1.f : 0.f; }
      imp[e] = si; ld[e] = sl;
    }
    float mi = 0.f, ml = 0.f;
    for (int e = 0; e < 8; ++e) { mi += imp[e]; ml += ld[e]; }
    mi *= 0.125f; ml *= 0.125f;
    float vi = 0.f, vl = 0.f;
    for (int e = 0; e < 8; ++e) {
      vi += (imp[e] - mi) * (imp[e] - mi);
      vl += (ld[e] - ml) * (ld[e] - ml);
    }
    vi /= 7.f; vl /= 7.f;
    loss_out[0] = 0.01f * (vi / (mi * mi + 1e-10f) + vl / (ml * ml + 1e-10f));
  }
}

// ---------------------------------------------------------------- fused: gemm (chunk k) | rec (k-1) | fold (k-2, L1)
// xw: ushort [ed2*2+bh][64 ss][512 n][16 b]; n = gate*128 + cell (pre-scaled values).
// LDS h slot: (cell,b) at byte (cell>>5)<<10 | ((cell>>3)&3)<<8 | b<<4 | (cell&7)<<1.
// h0: [e][1024 t][32 b][256];  h1 chunk ring: [e][64 ss][32 b][256] x2.
template <int L>
__global__ __launch_bounds__(512, 1) void fused(
    int k,
    const unsigned short* __restrict__ Asrc,
    const float* __restrict__ Wih, const float* __restrict__ bihp, const float* __restrict__ bhhp,
    const unsigned short* __restrict__ whhb,
    unsigned short* __restrict__ xwbufs,
    unsigned short* __restrict__ hstate, float* __restrict__ cstate,
    unsigned short* __restrict__ hout,
    const float* __restrict__ Mmat, const float* __restrict__ gatesp,
    float* __restrict__ outp) {
  constexpr int KC = L ? 8 : 4;
  constexpr int KS = KC * 32;
  const int tid = threadIdx.x, w = tid >> 6, l = tid & 63;
  const int l15 = l & 15, lq = l >> 4;

  if (L && blockIdx.x >= 192) {
    // ================= FOLD role: chunk c2 = k-2 =================
    const int c2 = k - 2;
    if (c2 < 0 || c2 > 15) return;
    if (w >= 6) return;
    const int ss = blockIdx.x - 192;
    const int mt = (w >= 3) ? 1 : 0, ot = w - mt * 3;
    const int o = ot * 16 + l15;
    const bool ov = o < 44;
    s16x8 bfm[2][4];
#pragma unroll
    for (int dd = 0; dd < 2; ++dd)
#pragma unroll
      for (int kc = 0; kc < 4; ++kc) {
        if (ov) bfm[dd][kc] = pack8s(Mmat + ((size_t)dd * 48 + o) * 128 + kc * 32 + lq * 8, 1.f);
        else { s16x8 z = {0,0,0,0,0,0,0,0}; bfm[dd][kc] = z; }
      }
    const unsigned short* hb = hout + (size_t)(c2 & 1) * 4194304;
    f32x4 acc0 = {0.f,0.f,0.f,0.f}, acc1 = {0.f,0.f,0.f,0.f};
    for (int e = 0; e < 8; ++e) {
      const unsigned short* ap = hb + ((((size_t)e * 64 + ss) * 32) + mt * 16 + l15) * 256 + lq * 8;
      f32x4 p0 = {0.f,0.f,0.f,0.f}, p1 = {0.f,0.f,0.f,0.f};
#pragma unroll
      for (int kc = 0; kc < 4; ++kc) {
        s16x8 a0 = *(const s16x8*)(ap + kc * 32);
        s16x8 a1 = *(const s16x8*)(ap + 128 + kc * 32);
        p0 = mfma16(a0, bfm[0][kc], p0);
        p1 = mfma16(a1, bfm[1][kc], p1);
      }
#pragma unroll
      for (int r = 0; r < 4; ++r) {
        const float g = gatesp[(mt * 16 + lq * 4 + r) * 8 + e];
        acc0[r] += g * p0[r];
        acc1[r] += g * p1[r];
      }
    }
    if (ov) {
      const int s2 = c2 * 64 + ss, t1 = 1023 - s2;
#pragma unroll
      for (int r = 0; r < 4; ++r) {
        const int b = mt * 16 + lq * 4 + r;
        outp[((size_t)s2 * 32 + b) * 44 + o] += acc0[r];
        outp[((size_t)t1 * 32 + b) * 44 + o] += acc1[r];
      }
    }
    return;
  }

  if (blockIdx.x >= 32) {
    // ================= GEMM role: xw chunk k =================
    if (k >= 16) return;
    const int gb = blockIdx.x - 32;
    const int ed = gb & 15, e = ed >> 1, d = ed & 1;
    const int slice = gb >> 4;
    const int nsl = L ? 10 : 14;
    unsigned short* xw = xwbufs + (size_t)(k & 1) * 16777216;

    s16x8 bf[4][KC];
    float bias[4];
#pragma unroll
    for (int j = 0; j < 4; ++j) {
      const int n = w * 64 + j * 16 + l15;
      const float sc = ((n >> 7) == 2) ? K2L : -LOG2E;
      bias[j] = (bihp[ed * 512 + n] + bhhp[ed * 512 + n]) * sc;
      const float* wp = Wih + ((size_t)ed * 512 + n) * KS + lq * 8;
#pragma unroll
      for (int kc = 0; kc < KC; ++kc) bf[j][kc] = pack8s(wp + kc * 32, sc);
    }
    for (int ss = slice; ss < 64; ss += nsl) {
      const int s = k * 64 + ss;
      const int t = d ? 1023 - s : s;
#pragma unroll
      for (int mt = 0; mt < 2; ++mt) {
        const size_t arow = (size_t)(L ? (e * 1024 + t) : t) * 32 + mt * 16 + l15;
        const unsigned short* ap = Asrc + arow * KS + lq * 8;
        s16x8 af[KC];
#pragma unroll
        for (int kc = 0; kc < KC; ++kc) af[kc] = *(const s16x8*)(ap + kc * 32);
        f32x4 acc[4];
#pragma unroll
        for (int j = 0; j < 4; ++j) acc[j] = f32x4{bias[j], bias[j], bias[j], bias[j]};
#pragma unroll
        for (int kc = 0; kc < KC; ++kc) {
#pragma unroll
          for (int j = 0; j < 4; ++j) acc[j] = mfma16(af[kc], bf[j][kc], acc[j]);
        }
        unsigned short* op = xw + (((size_t)(ed * 2 + mt) * 64 + ss) * 512) * 16 + lq * 4;
#pragma unroll
        for (int j = 0; j < 4; ++j) {
          const int n = w * 64 + j * 16 + l15;
          ushort4 o4;
          o4.x = f2bf(acc[j][0]); o4.y = f2bf(acc[j][1]);
          o4.z = f2bf(acc[j][2]); o4.w = f2bf(acc[j][3]);
          *(ushort4*)(op + (size_t)n * 16) = o4;
        }
      }
    }
    return;
  }

  // ================= REC role: chunk c = k-1 =================
  const int c = k - 1;
  if (c < 0 || c > 15) return;
  const int rb = blockIdx.x, ed2 = rb >> 1, bh = rb & 1;
  const int e = ed2 >> 1, d = ed2 & 1;
  __shared__ __align__(16) char hbf[2][4096];
  const int cell = w * 16 + l15;

  s16x8 bfh[4][4];  // pre-scaled Whh
#pragma unroll
  for (int g = 0; g < 4; ++g) {
    const unsigned short* wp = whhb + ((size_t)ed2 * 512 + g * 128 + cell) * 128 + lq * 8;
#pragma unroll
    for (int kc = 0; kc < 4; ++kc) bfh[g][kc] = *(const s16x8*)(wp + kc * 32);
  }
  const int wb0 = ((cell >> 5) << 10) | (((cell >> 3) & 3) << 8) | ((cell & 7) << 1);
  float cst[4];
  unsigned short hb4[4];
  if (c == 0) {
#pragma unroll
    for (int r = 0; r < 4; ++r) { cst[r] = 0.f; hb4[r] = 0; }
    if (tid < 256) {
      s16x8 z = {0,0,0,0,0,0,0,0};
      *(s16x8*)(&hbf[0][tid * 16]) = z;
    }
  } else {
    const float* cp = cstate + ((size_t)rb * 512 + tid) * 4;
    const unsigned short* hp = hstate + ((size_t)rb * 512 + tid) * 4;
#pragma unroll
    for (int r = 0; r < 4; ++r) {
      cst[r] = cp[r];
      hb4[r] = hp[r];
      *(unsigned short*)(&hbf[0][wb0 | ((lq * 4 + r) << 4)]) = hp[r];
    }
  }
  __syncthreads();

  const unsigned short* xwb =
      xwbufs + (size_t)(c & 1) * 16777216 + ((size_t)(ed2 * 2 + bh) * 64) * 8192 + cell * 16 + lq * 4;
  const int brow = bh * 16 + lq * 4;

  ushort4 xq[4];
#pragma unroll
  for (int g = 0; g < 4; ++g) xq[g] = *(const ushort4*)(xwb + g * 2048);

  for (int tt = 0; tt < 64; ++tt) {
    const int p = tt & 1;
    // early: prefetch next xw (full step to complete before barrier drain)
    ushort4 nxq[4];
    {
      const int tn = tt < 63 ? tt + 1 : 63;
#pragma unroll
      for (int g = 0; g < 4; ++g) nxq[g] = *(const ushort4*)(xwb + (size_t)tn * 8192 + g * 2048);
    }
    // early: store previous step's h from register carry
    if (tt > 0) {
      const int ptt = tt - 1;
      size_t ob;
      if (L) {
        ob = (size_t)(c & 1) * 4194304 + (((size_t)e * 64 + ptt) * 32 + brow) * 256 + d * 128 + cell;
      } else {
        const int s = c * 64 + ptt;
        const int tg = d ? 1023 - s : s;
        ob = (((size_t)e * 1024 + tg) * 32 + brow) * 256 + d * 128 + cell;
      }
#pragma unroll
      for (int r = 0; r < 4; ++r) hout[ob + (size_t)r * 256] = hb4[r];
    }

    s16x8 hf[4];
#pragma unroll
    for (int kc = 0; kc < 4; ++kc) hf[kc] = *(const s16x8*)(&hbf[p][kc * 1024 + l * 16]);
    f32x4 a[4];
#pragma unroll
    for (int g = 0; g < 4; ++g) {
      a[g][0] = bf2f(xq[g].x); a[g][1] = bf2f(xq[g].y);
      a[g][2] = bf2f(xq[g].z); a[g][3] = bf2f(xq[g].w);
    }
#pragma unroll
    for (int kc = 0; kc < 4; ++kc) {
#pragma unroll
      for (int g = 0; g < 4; ++g) a[g] = mfma16(hf[kc], bfh[g][kc], a[g]);
    }

    // gates (inputs pre-scaled: i/f/o by -log2e, g by 2log2e; cst pre-scaled by 2log2e)
#pragma unroll
    for (int r = 0; r < 4; ++r) {
      const float ai = ex2(a[0][r]);
      const float af = ex2(a[1][r]);
      const float bg = ex2(fminf(a[2][r], 80.f));
      const float ao = ex2(a[3][r]);
      const float sf = rcp_(1.f + af);
      const float r1 = rcp_((1.f + ai) * (1.f + bg));
      const float bgm = __builtin_fmaf(bg, K2L, -K2L);  // 2log2e*(bg-1)
      const float cc = __builtin_fmaf(sf, cst[r], bgm * r1);
      cst[r] = cc;
      const float qc = ex2(fminf(cc, 80.f));
      const float r2 = rcp_((1.f + ao) * (1.f + qc));
      hb4[r] = f2bf((qc - 1.f) * r2);
    }
    char* hw = &hbf[1 - p][0];
#pragma unroll
    for (int r = 0; r < 4; ++r)
      *(unsigned short*)(hw + (wb0 | ((lq * 4 + r) << 4))) = hb4[r];
    __syncthreads();
#pragma unroll
    for (int g = 0; g < 4; ++g) xq[g] = nxq[g];
  }

  // epilogue: store h(63) + carry state
  {
    size_t ob;
    if (L) {
      ob = (size_t)(c & 1) * 4194304 + (((size_t)e * 64 + 63) * 32 + brow) * 256 + d * 128 + cell;
    } else {
      const int s = c * 64 + 63;
      const int tg = d ? 1023 - s : s;
      ob = (((size_t)e * 1024 + tg) * 32 + brow) * 256 + d * 128 + cell;
    }
#pragma unroll
    for (int r = 0; r < 4; ++r) hout[ob + (size_t)r * 256] = hb4[r];
    unsigned short* hsp = hstate + ((size_t)rb * 512 + tid) * 4;
    float* csp = cstate + ((size_t)rb * 512 + tid) * 4;
#pragma unroll
    for (int r = 0; r < 4; ++r) { hsp[r] = hb4[r]; csp[r] = cst[r]; }
  }
}

// ---------------------------------------------------------------- launch
extern "C" void kernel_launch(void* const* d_in, const int* in_sizes, int n_in,
                              void* d_out, int out_size, void* d_ws, size_t ws_size,
                              hipStream_t stream) {
  const float* x    = (const float*)d_in[0];
  const float* spk  = (const float*)d_in[1];
  const float* wgw  = (const float*)d_in[2];
  const float* wgb  = (const float*)d_in[3];
  const float* Wih0 = (const float*)d_in[4];
  const float* Whh0 = (const float*)d_in[5];
  const float* bih0 = (const float*)d_in[6];
  const float* bhh0 = (const float*)d_in[7];
  const float* Wih1 = (const float*)d_in[8];
  const float* Whh1 = (const float*)d_in[9];
  const float* bih1 = (const float*)d_in[10];
  const float* bhh1 = (const float*)d_in[11];
  const float* fc1w = (const float*)d_in[12];
  const float* fc1b = (const float*)d_in[13];
  const float* fcw  = (const float*)d_in[14];
  const float* fcb  = (const float*)d_in[15];
  float* out = (float*)d_out;

  if (ws_size < (size_t)WS_NEED) {
    wsdbg_kernel<<<1, 1, 0, stream>>>(out, (float)(ws_size >> 20));
    return;
  }
  char* ws = (char*)d_ws;
  unsigned short* h0     = (unsigned short*)(ws + OFF_H0);
  unsigned short* xwbufs = (unsigned short*)(ws + OFF_XW);
  unsigned short* xt     = (unsigned short*)(ws + OFF_XT);
  unsigned short* whhb   = (unsigned short*)(ws + OFF_WHH);
  unsigned short* h1c    = (unsigned short*)(ws + OFF_H1C);
  unsigned short* hstate = (unsigned short*)(ws + OFF_HST);
  float*          cstate = (float*)(ws + OFF_CST);
  float*          Mmat   = (float*)(ws + OFF_M);
  float*          Cv     = (float*)(ws + OFF_CV);
  float*          gatesw = (float*)(ws + OFF_G);

  prepw_kernel<<<4096, 512, 0, stream>>>(Whh0, Whh1, whhb);
  prepx_kernel<<<4096, 512, 0, stream>>>(x, xt);
  mprep_kernel<<<48, 256, 0, stream>>>(fc1w, fc1b, fcw, fcb, Mmat, Cv);
  initout_kernel<<<2816, 512, 0, stream>>>(Cv, out);
  gating_kernel<<<1, 256, 0, stream>>>(spk, wgw, wgb, gatesw, out + 1441792);

  for (int k = 0; k <= 16; ++k)
    fused<0><<<256, 512, 0, stream>>>(k, xt, Wih0, bih0, bhh0, whhb, xwbufs,
                                      hstate, cstate, h0, nullptr, nullptr, out);
  for (int k = 0; k <= 17; ++k)
    fused<1><<<256, 512, 0, stream>>>(k, h0, Wih1, bih1, bhh1, whhb + 1048576, xwbufs,
                                      hstate, cstate, h1c, Mmat, gatesw, out);
}